// Round 2
// baseline (272.902 us; speedup 1.0000x reference)
//
#include <hip/hip_runtime.h>

#define NDEPTH 8
#define NK 129
#define SEQB 4096
#define DIM 512

typedef short bf16x8 __attribute__((ext_vector_type(8)));   // 8 bf16 in 4 VGPRs
typedef float f32x4  __attribute__((ext_vector_type(4)));

// ---------------------------------------------------------------------------
// Compile-time replication of the reference float64 Cantor-index pipeline
// (bit-exact: (1/3)*4095 truncates to 1364, not 1365).
// ---------------------------------------------------------------------------
struct CTab { int uidx[NK]; int minD[NK]; int count; };

static constexpr CTab make_ctab() {
    CTab T{};
    double pos[NDEPTH][NK] = {}; int cnt[NDEPTH] = {};
    pos[0][0] = 0.0; pos[0][1] = 1.0; cnt[0] = 2;
    for (int d = 1; d < NDEPTH; ++d) {
        const int n = cnt[d - 1]; int m = 0;
        for (int i = 0; i < n - 1; ++i) {
            const double left = pos[d - 1][i], right = pos[d - 1][i + 1];
            const double third = (right - left) / 3.0;
            pos[d][m++] = left; pos[d][m++] = left + third;
        }
        pos[d][m++] = pos[d - 1][n - 1]; cnt[d] = m;
    }
    int idx[NDEPTH][NK] = {}; int icnt[NDEPTH] = {};
    for (int d = 0; d < NDEPTH; ++d) {
        int m = 0;
        for (int i = 0; i < cnt[d]; ++i) {
            const long long v = (long long)(pos[d][i] * 4095.0);
            bool dup = false;
            for (int k = 0; k < m; ++k) if (idx[d][k] == (int)v) dup = true;
            if (!dup) idx[d][m++] = (int)v;
        }
        icnt[d] = m;
    }
    int u[2 * NK] = {}; int un = 0;
    for (int d = 0; d < NDEPTH; ++d)
        for (int i = 0; i < icnt[d]; ++i) {
            const int v = idx[d][i]; bool f = false;
            for (int k = 0; k < un; ++k) if (u[k] == v) f = true;
            if (!f && un < 2 * NK) u[un++] = v;
        }
    for (int i = 1; i < un; ++i) {
        const int key = u[i]; int k = i - 1;
        while (k >= 0 && u[k] > key) { u[k + 1] = u[k]; --k; }
        u[k + 1] = key;
    }
    T.count = un;
    for (int i = 0; i < un && i < NK; ++i) {
        T.uidx[i] = u[i];
        int md = NDEPTH;
        for (int d = 0; d < NDEPTH && md == NDEPTH; ++d)
            for (int k = 0; k < icnt[d]; ++k)
                if (idx[d][k] == u[i]) { md = d; break; }
        T.minD[i] = md;
    }
    return T;
}
static constexpr CTab h_ct = make_ctab();
static_assert(h_ct.count == NK, "cantor union size mismatch");
__device__ __constant__ CTab g_ct = h_ct;

__device__ __forceinline__ short f2bf(float f) {       // RNE f32->bf16
    union { float f; unsigned u; } v; v.f = f;
    unsigned r = v.u + 0x7fffu + ((v.u >> 16) & 1u);
    return (short)(r >> 16);
}

// ws layout: wsK [8][144][512] bf16 (rows>=129 zero)  = 1,179,648 B
//            wsVt[8][512][192] bf16 (keys>=129 zero)  = 1,572,864 B
#define WSK_ELEMS (8 * 144 * 512)

// ---------------------------------------------------------------------------
// Prep: build bf16 K-union rows + transposed V-union.
// ---------------------------------------------------------------------------
__global__ __launch_bounds__(256) void ufa_prep(
    const float* __restrict__ K, const float* __restrict__ V,
    short* __restrict__ ws)
{
    short* wsK  = ws;
    short* wsVt = ws + WSK_ELEMS;
    if (blockIdx.x < 1152) {                       // K rows: 8 batches x 144
        const int b = blockIdx.x / 144, key = blockIdx.x % 144;
        short* dst = wsK + ((size_t)b * 144 + key) * 512;
        if (key < NK) {
            const float* src = K + ((size_t)b * SEQB + g_ct.uidx[key]) * DIM;
            for (int i = threadIdx.x; i < 512; i += 256) dst[i] = f2bf(src[i]);
        } else {
            for (int i = threadIdx.x; i < 512; i += 256) dst[i] = 0;
        }
    } else {                                       // Vt: 8 batches x 32 d-slices
        __shared__ float tr[16][132];
        const int id = blockIdx.x - 1152;
        const int b = id >> 5, dc = id & 31;       // 16 d-columns per block
        const float* Vb = V + (size_t)b * SEQB * DIM + dc * 16;
        const int kk = (int)threadIdx.x >> 4, d = (int)threadIdx.x & 15;
        #pragma unroll
        for (int it = 0; it < 9; ++it) {           // 16 k-rows per iter
            const int k = it * 16 + kk;
            if (k < NK) tr[d][k] = Vb[(size_t)g_ct.uidx[k] * DIM + d];
        }
        __syncthreads();
        short* dst = wsVt + ((size_t)b * 512 + dc * 16) * 192;
        for (int idx = threadIdx.x; idx < 16 * 192; idx += 256) {
            const int dd = idx / 192, k = idx - dd * 192;
            dst[idx] = (k < NK) ? f2bf(tr[dd][k]) : (short)0;
        }
    }
}

// ---------------------------------------------------------------------------
// Main: 2048 blocks x 256 threads (8192 waves = 4x round-1) — 16 q-rows per
// BLOCK, with the 4 waves splitting the D-reduction (Phase A), the key range
// (cooperative softmax), and the output columns (Phase B).
//   Phase A: wave w computes partial S[16][144] over D-chunk [w*128,w*128+128)
//            -> tree reduction in f32 LDS (stride 148: 2-way banks, free)
//   softmax: wave w owns q-rows w*4..w*4+3; 64 lanes span the 129 keys
//   Phase B: wave w computes Out columns [w*128, w*128+128)
// Fragments stream directly from the L2-resident bf16 workspace (no staging
// barriers); latency hidden by ~24 resident waves/CU.
// ---------------------------------------------------------------------------
#define SSTR 148                                   // f32 LDS stride (2-way free)
#define CSTR 168                                   // bf16 c_lds stride

__global__ __launch_bounds__(256, 6) void ufa_main(
    const float* __restrict__ Q, const short* __restrict__ ws,
    const float* __restrict__ SW, const float* __restrict__ ST,
    float* __restrict__ Out)
{
    __shared__ float sbuf[2][16][SSTR];            // partial S, 18.9 KB
    __shared__ short c_lds[16][CSTR];              // coefficients, 5.4 KB

    const short* wsK  = ws;
    const short* wsVt = ws + WSK_ELEMS;

    const int t    = (int)threadIdx.x;
    const int w    = t >> 6;
    const int lane = t & 63;
    const int m    = lane & 15;
    const int quad = lane >> 4;
    const int b    = (int)blockIdx.x >> 8;
    const int q0   = ((int)blockIdx.x & 255) << 4;

    // depth-weight softmax (redundant per thread)
    float wgt[NDEPTH];
    {
        const float it = 1.0f / ST[0];
        float mx = -3.0e38f;
        #pragma unroll
        for (int d = 0; d < NDEPTH; ++d) { wgt[d] = SW[d] * it; mx = fmaxf(mx, wgt[d]); }
        float sum = 0.0f;
        #pragma unroll
        for (int d = 0; d < NDEPTH; ++d) { wgt[d] = __expf(wgt[d] - mx); sum += wgt[d]; }
        const float is = 1.0f / sum;
        #pragma unroll
        for (int d = 0; d < NDEPTH; ++d) wgt[d] *= is;
    }

    // ---------------- Phase A: partial S over D-chunk w ------------------
    f32x4 acc[9];
    #pragma unroll
    for (int tt = 0; tt < 9; ++tt) acc[tt] = (f32x4){0.f, 0.f, 0.f, 0.f};

    const float* Qb = Q + ((size_t)b * SEQB + q0 + m) * DIM + w * 128;
    const short* Kb = wsK + (size_t)b * 144 * 512 + w * 128;

    #pragma unroll
    for (int ks = 0; ks < 4; ++ks) {
        const float* qp = Qb + ks * 32 + quad * 8;
        const float4 x = *(const float4*)qp;
        const float4 y = *(const float4*)(qp + 4);
        bf16x8 aq;
        aq[0] = f2bf(x.x); aq[1] = f2bf(x.y); aq[2] = f2bf(x.z); aq[3] = f2bf(x.w);
        aq[4] = f2bf(y.x); aq[5] = f2bf(y.y); aq[6] = f2bf(y.z); aq[7] = f2bf(y.w);
        #pragma unroll
        for (int tt = 0; tt < 9; ++tt) {
            const bf16x8 bk = *(const bf16x8*)&Kb[(size_t)(tt * 16 + m) * 512
                                                 + ks * 32 + quad * 8];
            acc[tt] = __builtin_amdgcn_mfma_f32_16x16x32_bf16(aq, bk, acc[tt], 0, 0, 0);
        }
    }

    // tree-reduce the 4 partials into sbuf[0] + sbuf[1]
    if (w & 1) {                                   // waves 1,3 write
        float* Bf = &sbuf[w >> 1][0][0];
        #pragma unroll
        for (int tt = 0; tt < 9; ++tt)
            #pragma unroll
            for (int i = 0; i < 4; ++i)
                Bf[(quad * 4 + i) * SSTR + tt * 16 + m] = acc[tt][i];
    }
    __syncthreads();
    if (!(w & 1)) {                                // waves 0,2 accumulate
        float* Bf = &sbuf[w >> 1][0][0];
        #pragma unroll
        for (int tt = 0; tt < 9; ++tt)
            #pragma unroll
            for (int i = 0; i < 4; ++i) {
                const int a = (quad * 4 + i) * SSTR + tt * 16 + m;
                Bf[a] += acc[tt][i];
            }
    }
    __syncthreads();

    // ---------------- cooperative softmax: wave w owns rows w*4..w*4+3 ----
    const float inv_scale = 0.04419417382415922f;
    const int k0 = lane, k1 = 64 + lane, k2 = 128 + lane;
    const int  md0 = g_ct.minD[k0];                // lane < 64 < 129: valid
    const int  md1 = g_ct.minD[k1];                // 64..127: valid
    const bool v2  = (k2 < NK);                    // lane 0 only
    float cr0[4], cr1[4], cr2[4];

    #pragma unroll
    for (int rr = 0; rr < 4; ++rr) {
        const int r = w * 4 + rr;
        const float S0 = (sbuf[0][r][k0] + sbuf[1][r][k0]) * inv_scale;
        const float S1 = (sbuf[0][r][k1] + sbuf[1][r][k1]) * inv_scale;
        const float S2 = v2 ? (sbuf[0][r][128] + sbuf[1][r][128]) * inv_scale : -3.0e38f;
        float mx = fmaxf(fmaxf(S0, S1), S2);
        #pragma unroll
        for (int off = 1; off < 64; off <<= 1) mx = fmaxf(mx, __shfl_xor(mx, off));

        const float e0 = __expf(S0 - mx);
        const float e1 = __expf(S1 - mx);
        const float e2 = v2 ? __expf(S2 - mx) : 0.0f;

        float P[NDEPTH];
        #pragma unroll
        for (int d = 0; d < NDEPTH; ++d)
            P[d] = ((md0 == d) ? e0 : 0.0f) + ((md1 == d) ? e1 : 0.0f)
                 + ((v2 && md0 == md0 && g_ct.minD[128] == d) ? e2 : 0.0f);
        #pragma unroll
        for (int off = 1; off < 64; off <<= 1)
            #pragma unroll
            for (int d = 0; d < NDEPTH; ++d) P[d] += __shfl_xor(P[d], off);

        float L = 0.0f, Tv[NDEPTH];
        #pragma unroll
        for (int d = 0; d < NDEPTH; ++d) { L += P[d]; Tv[d] = L; }   // cumsum
        float ta = 0.0f;
        #pragma unroll
        for (int d = NDEPTH - 1; d >= 0; --d) { ta += wgt[d] / Tv[d]; Tv[d] = ta; }

        float tv0 = 0.0f, tv1 = 0.0f, tv2 = 0.0f;
        #pragma unroll
        for (int d = 0; d < NDEPTH; ++d) {
            tv0 = (md0 == d) ? Tv[d] : tv0;
            tv1 = (md1 == d) ? Tv[d] : tv1;
            tv2 = (v2 && g_ct.minD[128] == d) ? Tv[d] : tv2;
        }
        cr0[rr] = e0 * tv0; cr1[rr] = e1 * tv1; cr2[rr] = e2 * tv2;
    }
    // write bf16 coefficients: keys lane, 64+lane; lanes 0..31 cover 128..159
    #pragma unroll
    for (int rr = 0; rr < 4; ++rr) {
        const int r = w * 4 + rr;
        c_lds[r][k0] = f2bf(cr0[rr]);
        c_lds[r][k1] = f2bf(cr1[rr]);
        if (lane < 32) c_lds[r][128 + lane] = (lane == 0) ? f2bf(cr2[rr]) : (short)0;
    }
    __syncthreads();

    // ---------------- Phase B: Out columns [w*128, w*128+128) -------------
    bf16x8 ac[5];
    #pragma unroll
    for (int ks = 0; ks < 5; ++ks)
        ac[ks] = *(const bf16x8*)&c_lds[m][ks * 32 + quad * 8];

    const short* Vtb = wsVt + (size_t)b * 512 * 192 + (size_t)w * 128 * 192;
    float* Ob = Out + ((size_t)b * SEQB + q0) * DIM + w * 128;

    #pragma unroll
    for (int nt = 0; nt < 8; ++nt) {
        f32x4 o = (f32x4){0.f, 0.f, 0.f, 0.f};
        #pragma unroll
        for (int ks = 0; ks < 5; ++ks) {
            const bf16x8 bv = *(const bf16x8*)&Vtb[(size_t)(nt * 16 + m) * 192
                                                   + ks * 32 + quad * 8];
            o = __builtin_amdgcn_mfma_f32_16x16x32_bf16(ac[ks], bv, o, 0, 0, 0);
        }
        #pragma unroll
        for (int i = 0; i < 4; ++i)
            Ob[(size_t)(quad * 4 + i) * DIM + nt * 16 + m] = o[i];
    }
}

// ---------------------------------------------------------------------------
extern "C" void kernel_launch(void* const* d_in, const int* in_sizes, int n_in,
                              void* d_out, int out_size, void* d_ws, size_t ws_size,
                              hipStream_t stream) {
    const float* Q  = (const float*)d_in[0];
    const float* K  = (const float*)d_in[1];
    const float* V  = (const float*)d_in[2];
    const float* SW = (const float*)d_in[4];
    const float* ST = (const float*)d_in[5];
    float* Out = (float*)d_out;
    short* ws  = (short*)d_ws;

    ufa_prep<<<dim3(1152 + 256), dim3(256), 0, stream>>>(K, V, ws);
    ufa_main<<<dim3(2048), dim3(256), 0, stream>>>(Q, ws, SW, ST, Out);
}

// Round 3
// 213.315 us; speedup vs baseline: 1.2793x; 1.2793x over previous
//
#include <hip/hip_runtime.h>

#define NDEPTH 8
#define NK 129
#define SEQB 4096
#define DIM 512

typedef short bf16x8 __attribute__((ext_vector_type(8)));   // 8 bf16 in 4 VGPRs
typedef float f32x4  __attribute__((ext_vector_type(4)));

// ---------------------------------------------------------------------------
// Compile-time replication of the reference float64 Cantor-index pipeline
// (bit-exact: (1/3)*4095 truncates to 1364, not 1365).
// ---------------------------------------------------------------------------
struct CTab { int uidx[NK]; int minD[NK]; int count; };

static constexpr CTab make_ctab() {
    CTab T{};
    double pos[NDEPTH][NK] = {}; int cnt[NDEPTH] = {};
    pos[0][0] = 0.0; pos[0][1] = 1.0; cnt[0] = 2;
    for (int d = 1; d < NDEPTH; ++d) {
        const int n = cnt[d - 1]; int m = 0;
        for (int i = 0; i < n - 1; ++i) {
            const double left = pos[d - 1][i], right = pos[d - 1][i + 1];
            const double third = (right - left) / 3.0;
            pos[d][m++] = left; pos[d][m++] = left + third;
        }
        pos[d][m++] = pos[d - 1][n - 1]; cnt[d] = m;
    }
    int idx[NDEPTH][NK] = {}; int icnt[NDEPTH] = {};
    for (int d = 0; d < NDEPTH; ++d) {
        int m = 0;
        for (int i = 0; i < cnt[d]; ++i) {
            const long long v = (long long)(pos[d][i] * 4095.0);
            bool dup = false;
            for (int k = 0; k < m; ++k) if (idx[d][k] == (int)v) dup = true;
            if (!dup) idx[d][m++] = (int)v;
        }
        icnt[d] = m;
    }
    int u[2 * NK] = {}; int un = 0;
    for (int d = 0; d < NDEPTH; ++d)
        for (int i = 0; i < icnt[d]; ++i) {
            const int v = idx[d][i]; bool f = false;
            for (int k = 0; k < un; ++k) if (u[k] == v) f = true;
            if (!f && un < 2 * NK) u[un++] = v;
        }
    for (int i = 1; i < un; ++i) {
        const int key = u[i]; int k = i - 1;
        while (k >= 0 && u[k] > key) { u[k + 1] = u[k]; --k; }
        u[k + 1] = key;
    }
    T.count = un;
    for (int i = 0; i < un && i < NK; ++i) {
        T.uidx[i] = u[i];
        int md = NDEPTH;
        for (int d = 0; d < NDEPTH && md == NDEPTH; ++d)
            for (int k = 0; k < icnt[d]; ++k)
                if (idx[d][k] == u[i]) { md = d; break; }
        T.minD[i] = md;
    }
    return T;
}
static constexpr CTab h_ct = make_ctab();
static_assert(h_ct.count == NK, "cantor union size mismatch");
__device__ __constant__ CTab g_ct = h_ct;

__device__ __forceinline__ short f2bf(float f) {       // RNE f32->bf16
    union { float f; unsigned u; } v; v.f = f;
    unsigned r = v.u + 0x7fffu + ((v.u >> 16) & 1u);
    return (short)(r >> 16);
}

// ws layout: wsK [8][144][512] bf16 (rows>=129 zero)  = 1,179,648 B
//            wsVt[8][512][160] bf16 (keys>=129 zero)  = 1,310,720 B
#define WSK_ELEMS (8 * 144 * 512)

// ---------------------------------------------------------------------------
// Prep: build bf16 K-union rows + transposed V-union.
// ---------------------------------------------------------------------------
__global__ __launch_bounds__(256) void ufa_prep(
    const float* __restrict__ K, const float* __restrict__ V,
    short* __restrict__ ws)
{
    short* wsK  = ws;
    short* wsVt = ws + WSK_ELEMS;
    if (blockIdx.x < 1152) {                       // K rows: 8 batches x 144
        const int b = blockIdx.x / 144, key = blockIdx.x % 144;
        short* dst = wsK + ((size_t)b * 144 + key) * 512;
        if (key < NK) {
            const float* src = K + ((size_t)b * SEQB + g_ct.uidx[key]) * DIM;
            for (int i = threadIdx.x; i < 512; i += 256) dst[i] = f2bf(src[i]);
        } else {
            for (int i = threadIdx.x; i < 512; i += 256) dst[i] = 0;
        }
    } else {                                       // Vt: 8 batches x 32 d-slices
        __shared__ float tr[16][132];
        const int id = blockIdx.x - 1152;
        const int b = id >> 5, dc = id & 31;       // 16 d-columns per block
        const float* Vb = V + (size_t)b * SEQB * DIM + dc * 16;
        const int kk = (int)threadIdx.x >> 4, d = (int)threadIdx.x & 15;
        #pragma unroll
        for (int it = 0; it < 9; ++it) {           // 16 k-rows per iter
            const int k = it * 16 + kk;
            if (k < NK) tr[d][k] = Vb[(size_t)g_ct.uidx[k] * DIM + d];
        }
        __syncthreads();
        short* dst = wsVt + ((size_t)b * 512 + dc * 16) * 160;
        for (int idx = threadIdx.x; idx < 16 * 160; idx += 256) {
            const int dd = idx / 160, k = idx - dd * 160;
            dst[idx] = (k < NK) ? f2bf(tr[dd][k]) : (short)0;
        }
    }
}

// ---------------------------------------------------------------------------
// Main: 512 blocks x 256 threads (4 waves, 16 q-rows each => 64 rows/block),
// 2 blocks/CU. Double-buffered LDS chunk pipeline:
//   Phase A: 8 K-chunks [144 keys][64 d] (LDS stride 144B: banks 4 mod 32 ->
//            2-way-free b128 reads). Q held entirely in registers (64 VGPR).
//   Phase B: 8 V-chunks [64 d][160 k] (stride 336B, same bank property).
// Next chunk's global loads issue BEFORE compute, ds_writes land during
// compute into the other buffer, one barrier per chunk (drain hidden).
// LDS overlay (63 KB static): A: K0@0,K1@20736 | transition: c_lds@0 (43008)
// | B: V0@43008, V1@0 (c_lds dead after ac[] regs loaded).
// ---------------------------------------------------------------------------
#define KCH 20736                      // 144 * 144B
#define VCH 21504                      // 64 * 336B
#define V0_OFF 43008
#define SMEM_BYTES 64512

__global__ __launch_bounds__(256, 2) void ufa_main(
    const float* __restrict__ Q, const short* __restrict__ ws,
    const float* __restrict__ SW, const float* __restrict__ ST,
    float* __restrict__ Out)
{
    __shared__ char smem[SMEM_BYTES];

    const short* wsK  = ws;
    const short* wsVt = ws + WSK_ELEMS;

    const int t    = (int)threadIdx.x;
    const int w    = t >> 6;
    const int lane = t & 63;
    const int m    = lane & 15;
    const int quad = lane >> 4;
    const int b    = (int)blockIdx.x >> 6;          // 64 blocks per batch
    const int q0w  = (((int)blockIdx.x & 63) << 6) + w * 16;   // wave's rows

    const short* wsKb  = wsK  + (size_t)b * 144 * 512;
    const short* wsVtb = wsVt + (size_t)b * 512 * 160;

    // depth-weight softmax (redundant per thread)
    float wgt[NDEPTH];
    {
        const float it = 1.0f / ST[0];
        float mx = -3.0e38f;
        #pragma unroll
        for (int d = 0; d < NDEPTH; ++d) { wgt[d] = SW[d] * it; mx = fmaxf(mx, wgt[d]); }
        float sum = 0.0f;
        #pragma unroll
        for (int d = 0; d < NDEPTH; ++d) { wgt[d] = __expf(wgt[d] - mx); sum += wgt[d]; }
        const float is = 1.0f / sum;
        #pragma unroll
        for (int d = 0; d < NDEPTH; ++d) wgt[d] *= is;
    }

    // ---------------- K chunk staging helpers ----------------------------
    // chunk c: LDS [144 rows][72 shorts] (64 data + 8 pad), 1152 16B pieces.
    bf16x8 sreg[5];
    #define K_LOAD(c)                                                        \
        _Pragma("unroll")                                                    \
        for (int j = 0; j < 5; ++j) {                                        \
            const int i = t + j * 256;                                       \
            if (i < 1152) {                                                  \
                const int r = i >> 3, p = i & 7;                             \
                sreg[j] = *(const bf16x8*)(wsKb + (size_t)r * 512 + (c) * 64 + p * 8); \
            }                                                                \
        }
    #define K_WRITE(c)                                                       \
        {   char* dbuf = smem + ((c) & 1) * KCH;                             \
            _Pragma("unroll")                                                \
            for (int j = 0; j < 5; ++j) {                                    \
                const int i = t + j * 256;                                   \
                if (i < 1152) {                                              \
                    const int r = i >> 3, p = i & 7;                         \
                    *(bf16x8*)(dbuf + r * 144 + p * 16) = sreg[j];           \
                }                                                            \
            }                                                                \
        }

    // ---------------- Phase A: S = Q.K^T ---------------------------------
    K_LOAD(0);

    // preload all Q fragments for this wave's 16 rows (bf16, 64 VGPRs)
    bf16x8 qf[16];
    const float* Qb = Q + ((size_t)b * SEQB + q0w + m) * DIM;
    #pragma unroll
    for (int ks = 0; ks < 16; ++ks) {
        const float* qp = Qb + ks * 32 + quad * 8;
        const float4 x = *(const float4*)qp;
        const float4 y = *(const float4*)(qp + 4);
        qf[ks][0] = f2bf(x.x); qf[ks][1] = f2bf(x.y);
        qf[ks][2] = f2bf(x.z); qf[ks][3] = f2bf(x.w);
        qf[ks][4] = f2bf(y.x); qf[ks][5] = f2bf(y.y);
        qf[ks][6] = f2bf(y.z); qf[ks][7] = f2bf(y.w);
    }

    K_WRITE(0);
    __syncthreads();

    f32x4 acc[9];
    #pragma unroll
    for (int tt = 0; tt < 9; ++tt) acc[tt] = (f32x4){0.f, 0.f, 0.f, 0.f};

    for (int c = 0; c < 8; ++c) {
        if (c < 7) { K_LOAD(c + 1); }              // prefetch next chunk
        const char* buf = smem + (c & 1) * KCH;
        #pragma unroll
        for (int kk = 0; kk < 2; ++kk) {
            #pragma unroll
            for (int tt = 0; tt < 9; ++tt) {
                const bf16x8 bk = *(const bf16x8*)(buf + (tt * 16 + m) * 144
                                                   + (kk * 4 + quad) * 16);
                acc[tt] = __builtin_amdgcn_mfma_f32_16x16x32_bf16(
                              qf[c * 2 + kk], bk, acc[tt], 0, 0, 0);
            }
        }
        if (c < 7) { K_WRITE(c + 1); }             // land during/after compute
        __syncthreads();
    }

    // ---------------- V chunk 0 prefetch (hide under softmax) -------------
    // chunk c2: LDS [64 d-rows][168 shorts] (160 data + 8 pad), 1280 pieces.
    bf16x8 vreg[5];
    #pragma unroll
    for (int j = 0; j < 5; ++j) {
        const int i = t + j * 256;
        const int r = i / 20, p = i - r * 20;
        vreg[j] = *(const bf16x8*)(wsVtb + (size_t)r * 160 + p * 8);
    }

    // ---------------- softmax in MFMA C-layout ----------------------------
    // lane holds rows quad*4+i (i=0..3), keys j=16*tt+m (tt=0..8)
    const float inv_scale = 0.04419417382415922f;
    int md9[9];
    #pragma unroll
    for (int tt = 0; tt < 9; ++tt) {
        const int j = tt * 16 + m;
        md9[tt] = (j < NK) ? g_ct.minD[j] : NDEPTH;      // NDEPTH = invalid
    }
    float ev[9][4], mxr[4];
    #pragma unroll
    for (int i = 0; i < 4; ++i) mxr[i] = -3.0e38f;
    #pragma unroll
    for (int tt = 0; tt < 9; ++tt) {
        const bool valid = (tt * 16 + m) < NK;
        #pragma unroll
        for (int i = 0; i < 4; ++i) {
            const float s = valid ? acc[tt][i] * inv_scale : -3.0e38f;
            ev[tt][i] = s;
            mxr[i] = fmaxf(mxr[i], s);
        }
    }
    #pragma unroll
    for (int off = 1; off < 16; off <<= 1)
        #pragma unroll
        for (int i = 0; i < 4; ++i) mxr[i] = fmaxf(mxr[i], __shfl_xor(mxr[i], off));

    float P[4][NDEPTH];
    #pragma unroll
    for (int i = 0; i < 4; ++i)
        #pragma unroll
        for (int d = 0; d < NDEPTH; ++d) P[i][d] = 0.0f;
    #pragma unroll
    for (int tt = 0; tt < 9; ++tt) {
        const int md = md9[tt];
        #pragma unroll
        for (int i = 0; i < 4; ++i) {
            const float e = __expf(ev[tt][i] - mxr[i]);   // masked -> exp(-huge)=0
            ev[tt][i] = e;
            #pragma unroll
            for (int d = 0; d < NDEPTH; ++d) P[i][d] += (md == d) ? e : 0.0f;
        }
    }
    #pragma unroll
    for (int off = 1; off < 16; off <<= 1)
        #pragma unroll
        for (int i = 0; i < 4; ++i)
            #pragma unroll
            for (int d = 0; d < NDEPTH; ++d) P[i][d] += __shfl_xor(P[i][d], off);

    float T[4][NDEPTH];
    #pragma unroll
    for (int i = 0; i < 4; ++i) {
        float L = 0.0f, Lc[NDEPTH];
        #pragma unroll
        for (int d = 0; d < NDEPTH; ++d) { L += P[i][d]; Lc[d] = L; }
        float ta = 0.0f;
        #pragma unroll
        for (int d = NDEPTH - 1; d >= 0; --d) { ta += wgt[d] / Lc[d]; T[i][d] = ta; }
    }

    // write bf16 coefficients to c_lds: per wave [16 rows][168], keys<160
    short* c_lds = (short*)(smem) + w * (16 * 168);
    #pragma unroll
    for (int tt = 0; tt < 10; ++tt) {
        const int j = tt * 16 + m;
        #pragma unroll
        for (int i = 0; i < 4; ++i) {
            float cv = 0.0f;
            if (tt < 9 && j < NK) {
                const int md = md9[tt];
                float tv = 0.0f;
                #pragma unroll
                for (int d = 0; d < NDEPTH; ++d) tv = (md == d) ? T[i][d] : tv;
                cv = ev[tt][i] * tv;
            }
            c_lds[(quad * 4 + i) * 168 + j] = f2bf(cv);
        }
    }
    // read back as A-fragments (same wave wrote these rows; lgkm ordering
    // within wave + the barrier below orders against other waves' staging)
    bf16x8 ac[5];
    #pragma unroll
    for (int ks = 0; ks < 5; ++ks)
        ac[ks] = *(const bf16x8*)&c_lds[m * 168 + ks * 32 + quad * 8];

    // V chunk 0 -> LDS @ V0_OFF (does not touch c_lds region)
    #pragma unroll
    for (int j = 0; j < 5; ++j) {
        const int i = t + j * 256;
        const int r = i / 20, p = i - r * 20;
        *(bf16x8*)(smem + V0_OFF + r * 336 + p * 16) = vreg[j];
    }
    __syncthreads();

    // ---------------- Phase B: O = C.Vt ----------------------------------
    float* Ob = Out + ((size_t)b * SEQB + q0w) * DIM;

    for (int c2 = 0; c2 < 8; ++c2) {
        if (c2 < 7) {                               // prefetch next V chunk
            #pragma unroll
            for (int j = 0; j < 5; ++j) {
                const int i = t + j * 256;
                const int r = i / 20, p = i - r * 20;
                vreg[j] = *(const bf16x8*)(wsVtb + (size_t)(c2 + 1) * 64 * 160
                                           + (size_t)r * 160 + p * 8);
            }
        }
        const char* buf = smem + ((c2 & 1) ? 0 : V0_OFF);
        #pragma unroll
        for (int nt = 0; nt < 4; ++nt) {
            f32x4 o = (f32x4){0.f, 0.f, 0.f, 0.f};
            #pragma unroll
            for (int ks = 0; ks < 5; ++ks) {
                const bf16x8 bv = *(const bf16x8*)(buf + (nt * 16 + m) * 336
                                                   + (ks * 4 + quad) * 16);
                o = __builtin_amdgcn_mfma_f32_16x16x32_bf16(ac[ks], bv, o, 0, 0, 0);
            }
            const int n0 = c2 * 64 + nt * 16;
            #pragma unroll
            for (int i = 0; i < 4; ++i)
                Ob[(size_t)(quad * 4 + i) * DIM + n0 + m] = o[i];
        }
        if (c2 < 7) {
            char* dbuf = smem + ((c2 & 1) ? V0_OFF : 0);
            #pragma unroll
            for (int j = 0; j < 5; ++j) {
                const int i = t + j * 256;
                const int r = i / 20, p = i - r * 20;
                *(bf16x8*)(dbuf + r * 336 + p * 16) = vreg[j];
            }
        }
        __syncthreads();
    }
}

// ---------------------------------------------------------------------------
extern "C" void kernel_launch(void* const* d_in, const int* in_sizes, int n_in,
                              void* d_out, int out_size, void* d_ws, size_t ws_size,
                              hipStream_t stream) {
    const float* Q  = (const float*)d_in[0];
    const float* K  = (const float*)d_in[1];
    const float* V  = (const float*)d_in[2];
    const float* SW = (const float*)d_in[4];
    const float* ST = (const float*)d_in[5];
    float* Out = (float*)d_out;
    short* ws  = (short*)d_ws;

    ufa_prep<<<dim3(1152 + 256), dim3(256), 0, stream>>>(K, V, ws);
    ufa_main<<<dim3(512), dim3(256), 0, stream>>>(Q, ws, SW, ST, Out);
}

// Round 4
// 207.494 us; speedup vs baseline: 1.3152x; 1.0281x over previous
//
#include <hip/hip_runtime.h>

#define NDEPTH 8
#define NK 129
#define SEQB 4096
#define DIM 512

typedef short bf16x8 __attribute__((ext_vector_type(8)));   // 8 bf16 in 4 VGPRs
typedef short bf16x4 __attribute__((ext_vector_type(4)));
typedef float f32x4  __attribute__((ext_vector_type(4)));

// ---------------------------------------------------------------------------
// Compile-time replication of the reference float64 Cantor-index pipeline
// (bit-exact: (1/3)*4095 truncates to 1364, not 1365).
// Additionally produces a DEPTH-SORTED union (sidx) and bucket boundaries SB:
// keys grouped by minD so depth membership is a compile-time step function.
// ---------------------------------------------------------------------------
struct CTab {
    int uidx[NK]; int minD[NK];
    int sidx[NK];                 // union indices sorted by (minD, idx)
    int SB[NDEPTH + 1];           // bucket boundaries in sorted order
    int count;
};

static constexpr CTab make_ctab() {
    CTab T{};
    double pos[NDEPTH][NK] = {}; int cnt[NDEPTH] = {};
    pos[0][0] = 0.0; pos[0][1] = 1.0; cnt[0] = 2;
    for (int d = 1; d < NDEPTH; ++d) {
        const int n = cnt[d - 1]; int m = 0;
        for (int i = 0; i < n - 1; ++i) {
            const double left = pos[d - 1][i], right = pos[d - 1][i + 1];
            const double third = (right - left) / 3.0;
            pos[d][m++] = left; pos[d][m++] = left + third;
        }
        pos[d][m++] = pos[d - 1][n - 1]; cnt[d] = m;
    }
    int idx[NDEPTH][NK] = {}; int icnt[NDEPTH] = {};
    for (int d = 0; d < NDEPTH; ++d) {
        int m = 0;
        for (int i = 0; i < cnt[d]; ++i) {
            const long long v = (long long)(pos[d][i] * 4095.0);
            bool dup = false;
            for (int k = 0; k < m; ++k) if (idx[d][k] == (int)v) dup = true;
            if (!dup) idx[d][m++] = (int)v;
        }
        icnt[d] = m;
    }
    int u[2 * NK] = {}; int un = 0;
    for (int d = 0; d < NDEPTH; ++d)
        for (int i = 0; i < icnt[d]; ++i) {
            const int v = idx[d][i]; bool f = false;
            for (int k = 0; k < un; ++k) if (u[k] == v) f = true;
            if (!f && un < 2 * NK) u[un++] = v;
        }
    for (int i = 1; i < un; ++i) {
        const int key = u[i]; int k = i - 1;
        while (k >= 0 && u[k] > key) { u[k + 1] = u[k]; --k; }
        u[k + 1] = key;
    }
    T.count = un;
    for (int i = 0; i < un && i < NK; ++i) {
        T.uidx[i] = u[i];
        int md = NDEPTH;
        for (int d = 0; d < NDEPTH && md == NDEPTH; ++d)
            for (int k = 0; k < icnt[d]; ++k)
                if (idx[d][k] == u[i]) { md = d; break; }
        T.minD[i] = md;
    }
    // counting sort by minD (stable in idx order)
    int n = 0;
    for (int d = 0; d < NDEPTH; ++d) {
        T.SB[d] = n;
        for (int i = 0; i < un && i < NK; ++i)
            if (T.minD[i] == d) T.sidx[n++] = T.uidx[i];
    }
    T.SB[NDEPTH] = n;
    return T;
}
static constexpr CTab h_ct = make_ctab();
static_assert(h_ct.count == NK, "cantor union size mismatch");
static_assert(h_ct.SB[NDEPTH] == NK, "sorted union size mismatch");
__device__ __constant__ CTab g_ct = h_ct;

// depth of a SORTED key index (compile-time foldable; key>=NK -> NDEPTH-1)
__host__ __device__ constexpr int depth_of(int key) {
    int d = NDEPTH - 1;
    for (int x = NDEPTH - 1; x >= 0; --x) if (key < h_ct.SB[x + 1]) d = x;
    return d;
}

__device__ __forceinline__ short f2bf(float f) {       // RNE f32->bf16
    union { float f; unsigned u; } v; v.f = f;
    unsigned r = v.u + 0x7fffu + ((v.u >> 16) & 1u);
    return (short)(r >> 16);
}

__device__ __forceinline__ void gl_lds16(const void* g, void* lds) {
    __builtin_amdgcn_global_load_lds(
        (const __attribute__((address_space(1))) unsigned int*)g,
        (__attribute__((address_space(3))) unsigned int*)lds, 16, 0, 0);
}

// ws layout: wsK [8][144][512] bf16 (rows>=129 zero, DEPTH-SORTED) = 1,179,648 B
//            wsVt[8][512][192] bf16 (keys>=129 zero, DEPTH-SORTED) = 1,572,864 B
#define WSK_ELEMS (8 * 144 * 512)

// ---------------------------------------------------------------------------
// Prep: build bf16 K-union rows + transposed V-union, in depth-sorted order.
// ---------------------------------------------------------------------------
__global__ __launch_bounds__(256) void ufa_prep(
    const float* __restrict__ K, const float* __restrict__ V,
    short* __restrict__ ws)
{
    short* wsK  = ws;
    short* wsVt = ws + WSK_ELEMS;
    if (blockIdx.x < 1152) {                       // K rows: 8 batches x 144
        const int b = blockIdx.x / 144, key = blockIdx.x % 144;
        short* dst = wsK + ((size_t)b * 144 + key) * 512;
        if (key < NK) {
            const float* src = K + ((size_t)b * SEQB + g_ct.sidx[key]) * DIM;
            for (int i = threadIdx.x; i < 512; i += 256) dst[i] = f2bf(src[i]);
        } else {
            for (int i = threadIdx.x; i < 512; i += 256) dst[i] = 0;
        }
    } else {                                       // Vt: 8 batches x 32 d-slices
        __shared__ float tr[16][132];
        const int id = blockIdx.x - 1152;
        const int b = id >> 5, dc = id & 31;       // 16 d-columns per block
        const float* Vb = V + (size_t)b * SEQB * DIM + dc * 16;
        const int kk = (int)threadIdx.x >> 4, d = (int)threadIdx.x & 15;
        #pragma unroll
        for (int it = 0; it < 9; ++it) {           // 16 k-rows per iter
            const int k = it * 16 + kk;
            if (k < NK) tr[d][k] = Vb[(size_t)g_ct.sidx[k] * DIM + d];
        }
        __syncthreads();
        short* dst = wsVt + ((size_t)b * 512 + dc * 16) * 192;
        for (int idx = threadIdx.x; idx < 16 * 192; idx += 256) {
            const int dd = idx / 192, k = idx - dd * 192;
            dst[idx] = (k < NK) ? f2bf(tr[dd][k]) : (short)0;
        }
    }
}

// ---------------------------------------------------------------------------
// Main: 512 blocks x 256 threads (4 waves x 16 q-rows). Round-0 staging
// (gl_lds + XOR swizzle) but double-buffered with ONE barrier per chunk.
// Both MFMAs use SWAPPED operands:
//   Phase A: acc = mfma(K-frag, Q-frag)  -> lane holds (key, qrow=m):
//            softmax is lane-local along keys, reduced over quads only.
//   Phase B: o = mfma(V-frag, c-frag)    -> lane holds 4 consecutive out
//            columns -> float4 stores.
// LDS overlay (62976 B): A: Kbuf0@0, Kbuf1@18432, c_lds@36864 (25600)
//                        B: Vbuf0@0, Vbuf1@24576 (clobbers c_lds after ac[]).
// ---------------------------------------------------------------------------
#define KCH 18432                      // 144 * 128B
#define VCH 24576                      // 64 * 384B
#define CLDS_OFF 36864
#define CSTR 200                       // shorts; 400B row (16B-aligned)
#define SMEM_BYTES 62976

__global__ __launch_bounds__(256, 2) void ufa_main(
    const float* __restrict__ Q, const short* __restrict__ ws,
    const float* __restrict__ SW, const float* __restrict__ ST,
    float* __restrict__ Out)
{
    __shared__ char smem[SMEM_BYTES];

    const short* wsK  = ws;
    const short* wsVt = ws + WSK_ELEMS;

    const int t    = (int)threadIdx.x;
    const int w    = t >> 6;
    const int lane = t & 63;
    const int m    = lane & 15;
    const int quad = lane >> 4;
    const int b    = (int)blockIdx.x >> 6;
    const int q0w  = (((int)blockIdx.x & 63) << 6) + w * 16;

    const short* wsKb  = wsK  + (size_t)b * 144 * 512;
    const short* wsVb  = wsVt + (size_t)b * 512 * 192;

    // depth-weight softmax (redundant per thread)
    float wgt[NDEPTH];
    {
        const float it = 1.0f / ST[0];
        float mx = -3.0e38f;
        #pragma unroll
        for (int d = 0; d < NDEPTH; ++d) { wgt[d] = SW[d] * it; mx = fmaxf(mx, wgt[d]); }
        float sum = 0.0f;
        #pragma unroll
        for (int d = 0; d < NDEPTH; ++d) { wgt[d] = __expf(wgt[d] - mx); sum += wgt[d]; }
        const float is = 1.0f / sum;
        #pragma unroll
        for (int d = 0; d < NDEPTH; ++d) wgt[d] *= is;
    }

    // ---------------- staging helpers (round-0 swizzle, verbatim) --------
    #define STAGE_K(c, dst)                                                  \
        for (int g = w; g < 18; g += 4) {                                    \
            const int off  = g * 1024 + lane * 16;                           \
            const int row  = off >> 7;                                       \
            const int slot = (off >> 4) & 7;                                 \
            const int slog = slot ^ (row & 7);                               \
            gl_lds16(wsKb + (size_t)row * 512 + (c) * 64 + slog * 8,         \
                     (dst) + g * 1024);                                      \
        }
    #define STAGE_V(c2, dst)                                                 \
        for (int g = w; g < 24; g += 4) {                                    \
            const int off  = g * 1024 + lane * 16;                           \
            const int row  = off / 384;                                      \
            const int rem  = off - row * 384;                                \
            const int slot = rem >> 4;                                       \
            const int slog = (slot & ~7) | ((slot & 7) ^ (row & 7));         \
            gl_lds16(wsVb + (size_t)((c2) * 64 + row) * 192 + slog * 8,      \
                     (dst) + g * 1024);                                      \
        }

    // ---------------- Phase A: S^T = K.Q^T (swapped operands) ------------
    char* const kbuf0 = smem;
    char* const kbuf1 = smem + KCH;

    STAGE_K(0, kbuf0);

    // preload all Q fragments for this wave's 16 rows (bf16, 64 VGPRs)
    bf16x8 qf[16];
    const float* Qb = Q + ((size_t)b * SEQB + q0w + m) * DIM;
    #pragma unroll
    for (int ks = 0; ks < 16; ++ks) {
        const float* qp = Qb + ks * 32 + quad * 8;
        const float4 x = *(const float4*)qp;
        const float4 y = *(const float4*)(qp + 4);
        qf[ks][0] = f2bf(x.x); qf[ks][1] = f2bf(x.y);
        qf[ks][2] = f2bf(x.z); qf[ks][3] = f2bf(x.w);
        qf[ks][4] = f2bf(y.x); qf[ks][5] = f2bf(y.y);
        qf[ks][6] = f2bf(y.z); qf[ks][7] = f2bf(y.w);
    }
    __syncthreads();

    f32x4 acc[9];
    #pragma unroll
    for (int tt = 0; tt < 9; ++tt) acc[tt] = (f32x4){0.f, 0.f, 0.f, 0.f};

    for (int c = 0; c < 8; ++c) {
        if (c < 7) { STAGE_K(c + 1, (c & 1) ? kbuf0 : kbuf1); }
        const char* buf = (c & 1) ? kbuf1 : kbuf0;
        #pragma unroll
        for (int kk = 0; kk < 2; ++kk) {
            #pragma unroll
            for (int tt = 0; tt < 9; ++tt) {
                const int row  = tt * 16 + m;
                const int slog = (kk * 4 + quad) ^ (row & 7);
                const bf16x8 bk = *(const bf16x8*)(buf + row * 128 + slog * 16);
                // SWAPPED: A = K-frag, B = Q-frag  ->  acc = S^T tile
                acc[tt] = __builtin_amdgcn_mfma_f32_16x16x32_bf16(
                              bk, qf[c * 2 + kk], acc[tt], 0, 0, 0);
            }
        }
        __syncthreads();
    }

    // ---------------- V chunk 0 staging (hidden under softmax) ------------
    STAGE_V(0, smem);                              // Vbuf0 @ 0 (K region dead)

    // ---------------- lane-local softmax ---------------------------------
    // lane holds q-row m, keys tt*16 + quad*4 + i  (sorted by depth)
    const float inv_scale = 0.04419417382415922f;
    float ev[9][4];
    float mx = -3.0e38f;
    #pragma unroll
    for (int tt = 0; tt < 9; ++tt) {
        #pragma unroll
        for (int i = 0; i < 4; ++i) {
            float s = acc[tt][i] * inv_scale;
            if (tt == 8) s = (quad == 0 && i == 0) ? s : -3.0e38f;  // key 128 only
            ev[tt][i] = s;
            mx = fmaxf(mx, s);
        }
    }
    mx = fmaxf(mx, __shfl_xor(mx, 16));
    mx = fmaxf(mx, __shfl_xor(mx, 32));

    float P[NDEPTH];
    #pragma unroll
    for (int d = 0; d < NDEPTH; ++d) P[d] = 0.0f;
    #pragma unroll
    for (int tt = 0; tt < 9; ++tt) {
        const int dLo = depth_of(tt * 16);
        const int dHi = depth_of(tt * 16 + 15 < NK ? tt * 16 + 15 : NK - 1);
        #pragma unroll
        for (int i = 0; i < 4; ++i) {
            const float e = __expf(ev[tt][i] - mx);   // masked -> 0
            ev[tt][i] = e;
            if (dLo == dHi) {
                P[dLo] += e;
            } else {
                const int key = tt * 16 + quad * 4 + i;
                #pragma unroll
                for (int d = dLo; d <= dHi; ++d) {
                    const bool in = (key >= h_ct.SB[d]) && (key < h_ct.SB[d + 1]);
                    P[d] += in ? e : 0.0f;
                }
            }
        }
    }
    #pragma unroll
    for (int d = 0; d < NDEPTH; ++d) {
        P[d] += __shfl_xor(P[d], 16);
        P[d] += __shfl_xor(P[d], 32);
    }

    float Lc = 0.0f, Tsf[NDEPTH];
    #pragma unroll
    for (int d = 0; d < NDEPTH; ++d) { Lc += P[d]; Tsf[d] = Lc; }
    {
        float ta = 0.0f;
        #pragma unroll
        for (int d = NDEPTH - 1; d >= 0; --d) { ta += wgt[d] / Tsf[d]; Tsf[d] = ta; }
    }

    // c coefficients -> bf16 packed b64 writes: c_lds[row m][key]
    short* crow = (short*)(smem + CLDS_OFF) + (w * 16 + m) * CSTR;
    #pragma unroll
    for (int tt = 0; tt < 9; ++tt) {
        const int dLo = depth_of(tt * 16);
        const int dHi = depth_of(tt * 16 + 15 < NK ? tt * 16 + 15 : NK - 1);
        bf16x4 pk;
        #pragma unroll
        for (int i = 0; i < 4; ++i) {
            float tv = Tsf[dLo];
            if (dLo != dHi) {
                const int key = tt * 16 + quad * 4 + i;
                #pragma unroll
                for (int d = dLo + 1; d <= dHi; ++d)
                    tv = (key >= h_ct.SB[d]) ? Tsf[d] : tv;
            }
            pk[i] = f2bf(ev[tt][i] * tv);
        }
        *(bf16x4*)(crow + tt * 16 + quad * 4) = pk;
    }
    *(bf16x4*)(crow + 144 + quad * 4) = (bf16x4){0, 0, 0, 0};   // keys 144..159

    __syncthreads();                               // c_lds visible, V0 drained

    // ---------------- Phase B: O^T = Vt.C^T (swapped operands) ------------
    bf16x8 ac[5];
    {
        const short* cr = (const short*)(smem + CLDS_OFF) + (w * 16 + m) * CSTR;
        #pragma unroll
        for (int ks = 0; ks < 5; ++ks)
            ac[ks] = *(const bf16x8*)(cr + ks * 32 + quad * 8);
    }
    __syncthreads();                               // ac read before V1 clobbers

    char* const vbuf0 = smem;
    char* const vbuf1 = smem + VCH;
    float* Obm = Out + ((size_t)b * SEQB + q0w + m) * DIM + quad * 4;

    for (int c2 = 0; c2 < 8; ++c2) {
        if (c2 < 7) { STAGE_V(c2 + 1, (c2 & 1) ? vbuf0 : vbuf1); }
        const char* buf = (c2 & 1) ? vbuf1 : vbuf0;
        #pragma unroll
        for (int nt = 0; nt < 4; ++nt) {
            f32x4 o = (f32x4){0.f, 0.f, 0.f, 0.f};
            #pragma unroll
            for (int ks = 0; ks < 5; ++ks) {
                const int row  = nt * 16 + m;
                const int slot = ks * 4 + quad;
                const int slog = (slot & ~7) | ((slot & 7) ^ (row & 7));
                const bf16x8 bv = *(const bf16x8*)(buf + row * 384 + slog * 16);
                // SWAPPED: A = V-frag, B = c-frag  ->  lane holds 4 out-cols
                o = __builtin_amdgcn_mfma_f32_16x16x32_bf16(bv, ac[ks], o, 0, 0, 0);
            }
            *(f32x4*)(Obm + c2 * 64 + nt * 16) = o;    // float4 store
        }
        if (c2 < 7) __syncthreads();
    }
}

// ---------------------------------------------------------------------------
extern "C" void kernel_launch(void* const* d_in, const int* in_sizes, int n_in,
                              void* d_out, int out_size, void* d_ws, size_t ws_size,
                              hipStream_t stream) {
    const float* Q  = (const float*)d_in[0];
    const float* K  = (const float*)d_in[1];
    const float* V  = (const float*)d_in[2];
    const float* SW = (const float*)d_in[4];
    const float* ST = (const float*)d_in[5];
    float* Out = (float*)d_out;
    short* ws  = (short*)d_ws;

    ufa_prep<<<dim3(1152 + 256), dim3(256), 0, stream>>>(K, V, ws);
    ufa_main<<<dim3(512), dim3(256), 0, stream>>>(Q, ws, SW, ST, Out);
}

// Round 5
// 206.363 us; speedup vs baseline: 1.3224x; 1.0055x over previous
//
#include <hip/hip_runtime.h>

#define NDEPTH 8
#define NK 129
#define SEQB 4096
#define DIM 512

typedef short bf16x8 __attribute__((ext_vector_type(8)));   // 8 bf16 in 4 VGPRs
typedef short bf16x4 __attribute__((ext_vector_type(4)));
typedef float f32x4  __attribute__((ext_vector_type(4)));

// ---------------------------------------------------------------------------
// Compile-time replication of the reference float64 Cantor-index pipeline
// (bit-exact: (1/3)*4095 truncates to 1364, not 1365).
// Produces a DEPTH-SORTED union (sidx) and bucket boundaries SB.
// ---------------------------------------------------------------------------
struct CTab {
    int uidx[NK]; int minD[NK];
    int sidx[NK];                 // union indices sorted by (minD, idx)
    int SB[NDEPTH + 1];           // bucket boundaries in sorted order
    int count;
};

static constexpr CTab make_ctab() {
    CTab T{};
    double pos[NDEPTH][NK] = {}; int cnt[NDEPTH] = {};
    pos[0][0] = 0.0; pos[0][1] = 1.0; cnt[0] = 2;
    for (int d = 1; d < NDEPTH; ++d) {
        const int n = cnt[d - 1]; int m = 0;
        for (int i = 0; i < n - 1; ++i) {
            const double left = pos[d - 1][i], right = pos[d - 1][i + 1];
            const double third = (right - left) / 3.0;
            pos[d][m++] = left; pos[d][m++] = left + third;
        }
        pos[d][m++] = pos[d - 1][n - 1]; cnt[d] = m;
    }
    int idx[NDEPTH][NK] = {}; int icnt[NDEPTH] = {};
    for (int d = 0; d < NDEPTH; ++d) {
        int m = 0;
        for (int i = 0; i < cnt[d]; ++i) {
            const long long v = (long long)(pos[d][i] * 4095.0);
            bool dup = false;
            for (int k = 0; k < m; ++k) if (idx[d][k] == (int)v) dup = true;
            if (!dup) idx[d][m++] = (int)v;
        }
        icnt[d] = m;
    }
    int u[2 * NK] = {}; int un = 0;
    for (int d = 0; d < NDEPTH; ++d)
        for (int i = 0; i < icnt[d]; ++i) {
            const int v = idx[d][i]; bool f = false;
            for (int k = 0; k < un; ++k) if (u[k] == v) f = true;
            if (!f && un < 2 * NK) u[un++] = v;
        }
    for (int i = 1; i < un; ++i) {
        const int key = u[i]; int k = i - 1;
        while (k >= 0 && u[k] > key) { u[k + 1] = u[k]; --k; }
        u[k + 1] = key;
    }
    T.count = un;
    for (int i = 0; i < un && i < NK; ++i) {
        T.uidx[i] = u[i];
        int md = NDEPTH;
        for (int d = 0; d < NDEPTH && md == NDEPTH; ++d)
            for (int k = 0; k < icnt[d]; ++k)
                if (idx[d][k] == u[i]) { md = d; break; }
        T.minD[i] = md;
    }
    int n = 0;
    for (int d = 0; d < NDEPTH; ++d) {
        T.SB[d] = n;
        for (int i = 0; i < un && i < NK; ++i)
            if (T.minD[i] == d) T.sidx[n++] = T.uidx[i];
    }
    T.SB[NDEPTH] = n;
    return T;
}
static constexpr CTab h_ct = make_ctab();
static_assert(h_ct.count == NK, "cantor union size mismatch");
static_assert(h_ct.SB[NDEPTH] == NK, "sorted union size mismatch");
__device__ __constant__ CTab g_ct = h_ct;

// depth of a SORTED key index (compile-time foldable)
__host__ __device__ constexpr int depth_of(int key) {
    int d = NDEPTH - 1;
    for (int x = NDEPTH - 1; x >= 0; --x) if (key < h_ct.SB[x + 1]) d = x;
    return d;
}

__device__ __forceinline__ short f2bf(float f) {       // RNE f32->bf16
    union { float f; unsigned u; } v; v.f = f;
    unsigned r = v.u + 0x7fffu + ((v.u >> 16) & 1u);
    return (short)(r >> 16);
}

__device__ __forceinline__ void gl_lds16(const void* g, void* lds) {
    __builtin_amdgcn_global_load_lds(
        (const __attribute__((address_space(1))) unsigned int*)g,
        (__attribute__((address_space(3))) unsigned int*)lds, 16, 0, 0);
}

// counted vmcnt wait + scheduling fence (rule #18)
#define WAITVM(n) do {                                                   \
        asm volatile("s_waitcnt vmcnt(" #n ")" ::: "memory");            \
        __builtin_amdgcn_sched_barrier(0);                               \
    } while (0)

// ws layout: wsK [8][144][512] bf16 (rows>=129 zero, DEPTH-SORTED) = 1,179,648 B
//            wsVt[8][512][192] bf16 (keys>=129 zero, DEPTH-SORTED) = 1,572,864 B
#define WSK_ELEMS (8 * 144 * 512)

// ---------------------------------------------------------------------------
// Prep: build bf16 K-union rows + transposed V-union, depth-sorted order.
// ---------------------------------------------------------------------------
__global__ __launch_bounds__(256) void ufa_prep(
    const float* __restrict__ K, const float* __restrict__ V,
    short* __restrict__ ws)
{
    short* wsK  = ws;
    short* wsVt = ws + WSK_ELEMS;
    if (blockIdx.x < 1152) {                       // K rows: 8 batches x 144
        const int b = blockIdx.x / 144, key = blockIdx.x % 144;
        unsigned* dst = (unsigned*)(wsK + ((size_t)b * 144 + key) * 512);
        if (key < NK) {
            const float* src = K + ((size_t)b * SEQB + g_ct.sidx[key]) * DIM;
            const float2 s = *(const float2*)(src + threadIdx.x * 2);
            dst[threadIdx.x] = ((unsigned)(unsigned short)f2bf(s.y) << 16)
                             | (unsigned short)f2bf(s.x);
        } else {
            dst[threadIdx.x] = 0u;
        }
    } else {                                       // Vt: 8 batches x 32 d-slices
        __shared__ float tr[16][132];
        const int id = blockIdx.x - 1152;
        const int b = id >> 5, dc = id & 31;       // 16 d-columns per block
        const float* Vb = V + (size_t)b * SEQB * DIM + dc * 16;
        const int kk = (int)threadIdx.x >> 4, d = (int)threadIdx.x & 15;
        #pragma unroll
        for (int it = 0; it < 9; ++it) {           // 16 k-rows per iter
            const int k = it * 16 + kk;
            if (k < NK) tr[d][k] = Vb[(size_t)g_ct.sidx[k] * DIM + d];
        }
        __syncthreads();
        short* dst = wsVt + ((size_t)b * 512 + dc * 16) * 192;
        for (int idx = threadIdx.x; idx < 16 * 192; idx += 256) {
            const int dd = idx / 192, k = idx - dd * 192;
            dst[idx] = (k < NK) ? f2bf(tr[dd][k]) : (short)0;
        }
    }
}

// ---------------------------------------------------------------------------
// Main: 512 blocks x 256 threads (4 waves x 16 q-rows). Round-4 swapped-MFMA
// structure, upgraded to a TRIPLE-BUFFERED, COUNTED-vmcnt pipeline (T3+T4):
// stage chunk c+2 while computing c; raw s_barrier with s_waitcnt vmcnt(N)
// (never 0 in steady state) so prefetch loads stay in flight across barriers.
// Per-wave staging counts made uniform: K chunk = [160 rows][64 d] (20 x 1KB
// groups = 5 gl_lds/wave), V chunk = [32 rows][192 k] (12 groups = 3/wave).
// LDS (62464 B): Phase A: kb0@0 kb1@20480 kb2@40960.
//   Transition/Phase B: c_lds@0 (25600, each wave reads only its own rows),
//   vb0@25600 vb1@37888 vb2@50176 (over dead kb space).
// ---------------------------------------------------------------------------
#define KCH 20480                      // 160 * 128B
#define VCH 12288                      // 32 * 384B
#define VB_BASE 25600
#define CSTR 200                       // shorts; 400B c_lds row
#define SMEM_BYTES 62464

__global__ __launch_bounds__(256, 2) void ufa_main(
    const float* __restrict__ Q, const short* __restrict__ ws,
    const float* __restrict__ SW, const float* __restrict__ ST,
    float* __restrict__ Out)
{
    __shared__ __align__(16) char smem[SMEM_BYTES];

    const short* wsK  = ws;
    const short* wsVt = ws + WSK_ELEMS;

    const int t    = (int)threadIdx.x;
    const int w    = t >> 6;
    const int lane = t & 63;
    const int m    = lane & 15;
    const int quad = lane >> 4;
    const int b    = (int)blockIdx.x >> 6;
    const int q0w  = (((int)blockIdx.x & 63) << 6) + w * 16;

    const short* wsKb = wsK  + (size_t)b * 144 * 512;
    const short* wsVb = wsVt + (size_t)b * 512 * 192;

    // depth-weight softmax (redundant per thread)
    float wgt[NDEPTH];
    {
        const float it = 1.0f / ST[0];
        float mx = -3.0e38f;
        #pragma unroll
        for (int d = 0; d < NDEPTH; ++d) { wgt[d] = SW[d] * it; mx = fmaxf(mx, wgt[d]); }
        float sum = 0.0f;
        #pragma unroll
        for (int d = 0; d < NDEPTH; ++d) { wgt[d] = __expf(wgt[d] - mx); sum += wgt[d]; }
        const float is = 1.0f / sum;
        #pragma unroll
        for (int d = 0; d < NDEPTH; ++d) wgt[d] *= is;
    }

    // ---------------- staging (XOR swizzle; uniform count per wave) -------
    // K: 20 groups -> 5 gl_lds per wave. Rows 144..159 read junk (in-bounds
    // of ws), never consumed by compute (tt<=8 -> rows<144).
    #define STAGE_K(c, dst)                                                  \
        for (int g = w; g < 20; g += 4) {                                    \
            const int off  = g * 1024 + lane * 16;                           \
            const int row  = off >> 7;                                       \
            const int slot = (off >> 4) & 7;                                 \
            const int slog = slot ^ (row & 7);                               \
            gl_lds16(wsKb + (size_t)row * 512 + (c) * 64 + slog * 8,         \
                     (dst) + g * 1024);                                      \
        }
    // V: 12 groups -> 3 gl_lds per wave; 32-row chunks.
    #define STAGE_V(c2, dst)                                                 \
        for (int g = w; g < 12; g += 4) {                                    \
            const int off  = g * 1024 + lane * 16;                           \
            const int row  = off / 384;                                      \
            const int rem  = off - row * 384;                                \
            const int slot = rem >> 4;                                       \
            const int slog = (slot & ~7) | ((slot & 7) ^ (row & 7));         \
            gl_lds16(wsVb + (size_t)((c2) * 32 + row) * 192 + slog * 8,      \
                     (dst) + g * 1024);                                      \
        }

    // ---------------- Phase A prologue -----------------------------------
    STAGE_K(0, smem);
    STAGE_K(1, smem + KCH);

    // preload all Q fragments for this wave's 16 rows (bf16, 64 VGPRs)
    bf16x8 qf[16];
    const float* Qb = Q + ((size_t)b * SEQB + q0w + m) * DIM;
    #pragma unroll
    for (int ks = 0; ks < 16; ++ks) {
        const float* qp = Qb + ks * 32 + quad * 8;
        const float4 x = *(const float4*)qp;
        const float4 y = *(const float4*)(qp + 4);
        qf[ks][0] = f2bf(x.x); qf[ks][1] = f2bf(x.y);
        qf[ks][2] = f2bf(x.z); qf[ks][3] = f2bf(x.w);
        qf[ks][4] = f2bf(y.x); qf[ks][5] = f2bf(y.y);
        qf[ks][6] = f2bf(y.z); qf[ks][7] = f2bf(y.w);
    }
    __syncthreads();                               // full drain once (counts=0)

    // ---------------- Phase A: S^T = K.Q^T, 2-deep pipeline ---------------
    f32x4 acc[9];
    #pragma unroll
    for (int tt = 0; tt < 9; ++tt) acc[tt] = (f32x4){0.f, 0.f, 0.f, 0.f};

    for (int c = 0; c < 8; ++c) {
        if (c < 6) { STAGE_K(c + 2, smem + ((c + 2) % 3) * KCH); }
        const char* buf = smem + (c % 3) * KCH;
        #pragma unroll
        for (int kk = 0; kk < 2; ++kk) {
            #pragma unroll
            for (int tt = 0; tt < 9; ++tt) {
                const int row  = tt * 16 + m;
                const int slog = (kk * 4 + quad) ^ (row & 7);
                const bf16x8 bk = *(const bf16x8*)(buf + row * 128 + slog * 16);
                acc[tt] = __builtin_amdgcn_mfma_f32_16x16x32_bf16(
                              bk, qf[c * 2 + kk], acc[tt], 0, 0, 0);
            }
        }
        if (c < 7) {
            if (c < 6) { WAITVM(5); } else { WAITVM(0); }   // c+1 landed; c+2 flying
            __builtin_amdgcn_s_barrier();
        }
    }
    __syncthreads();                               // end Phase A (all kb dead)

    // ---------------- V chunks 0,1 staged under softmax -------------------
    STAGE_V(0, smem + VB_BASE);
    STAGE_V(1, smem + VB_BASE + VCH);

    // ---------------- lane-local softmax ---------------------------------
    // lane holds q-row m, keys tt*16 + quad*4 + i  (sorted by depth)
    const float inv_scale = 0.04419417382415922f;
    float ev[9][4];
    float mx = -3.0e38f;
    #pragma unroll
    for (int tt = 0; tt < 9; ++tt) {
        #pragma unroll
        for (int i = 0; i < 4; ++i) {
            float s = acc[tt][i] * inv_scale;
            if (tt == 8) s = (quad == 0 && i == 0) ? s : -3.0e38f;  // key 128 only
            ev[tt][i] = s;
            mx = fmaxf(mx, s);
        }
    }
    mx = fmaxf(mx, __shfl_xor(mx, 16));
    mx = fmaxf(mx, __shfl_xor(mx, 32));

    float P[NDEPTH];
    #pragma unroll
    for (int d = 0; d < NDEPTH; ++d) P[d] = 0.0f;
    #pragma unroll
    for (int tt = 0; tt < 9; ++tt) {
        const int dLo = depth_of(tt * 16);
        const int dHi = depth_of(tt * 16 + 15 < NK ? tt * 16 + 15 : NK - 1);
        #pragma unroll
        for (int i = 0; i < 4; ++i) {
            const float e = __expf(ev[tt][i] - mx);   // masked -> 0
            ev[tt][i] = e;
            if (dLo == dHi) {
                P[dLo] += e;
            } else {
                const int key = tt * 16 + quad * 4 + i;
                #pragma unroll
                for (int d = dLo; d <= dHi; ++d) {
                    const bool in = (key >= h_ct.SB[d]) && (key < h_ct.SB[d + 1]);
                    P[d] += in ? e : 0.0f;
                }
            }
        }
    }
    #pragma unroll
    for (int d = 0; d < NDEPTH; ++d) {
        P[d] += __shfl_xor(P[d], 16);
        P[d] += __shfl_xor(P[d], 32);
    }

    float Lc = 0.0f, Tsf[NDEPTH];
    #pragma unroll
    for (int d = 0; d < NDEPTH; ++d) { Lc += P[d]; Tsf[d] = Lc; }
    {
        float ta = 0.0f;
        #pragma unroll
        for (int d = NDEPTH - 1; d >= 0; --d) { ta += wgt[d] / Tsf[d]; Tsf[d] = ta; }
    }

    // c coefficients -> bf16 b64 writes; each wave writes/reads ONLY its own
    // rows, so no cross-wave barrier is needed for c_lds itself.
    short* crow = (short*)smem + (w * 16 + m) * CSTR;
    #pragma unroll
    for (int tt = 0; tt < 9; ++tt) {
        const int dLo = depth_of(tt * 16);
        const int dHi = depth_of(tt * 16 + 15 < NK ? tt * 16 + 15 : NK - 1);
        bf16x4 pk;
        #pragma unroll
        for (int i = 0; i < 4; ++i) {
            float tv = Tsf[dLo];
            if (dLo != dHi) {
                const int key = tt * 16 + quad * 4 + i;
                #pragma unroll
                for (int d = dLo + 1; d <= dHi; ++d)
                    tv = (key >= h_ct.SB[d]) ? Tsf[d] : tv;
            }
            pk[i] = f2bf(ev[tt][i] * tv);
        }
        *(bf16x4*)(crow + tt * 16 + quad * 4) = pk;
    }
    *(bf16x4*)(crow + 144 + quad * 4) = (bf16x4){0, 0, 0, 0};   // keys 144..159

    bf16x8 ac[5];
    #pragma unroll
    for (int ks = 0; ks < 5; ++ks)
        ac[ks] = *(const bf16x8*)(crow - m * CSTR + m * CSTR + ks * 32 + quad * 8);

    // V0 landed (V1's 3 may fly); own ds ops retired before barrier.
    asm volatile("s_waitcnt vmcnt(3) lgkmcnt(0)" ::: "memory");
    __builtin_amdgcn_sched_barrier(0);
    __builtin_amdgcn_s_barrier();

    // ---------------- Phase B: O^T = Vt.C^T, 2-deep pipeline --------------
    float* Obm = Out + ((size_t)b * SEQB + q0w + m) * DIM + quad * 4;

    for (int c2 = 0; c2 < 16; ++c2) {
        if (c2 < 14) { STAGE_V(c2 + 2, smem + VB_BASE + ((c2 + 2) % 3) * VCH); }
        const char* buf = smem + VB_BASE + (c2 % 3) * VCH;
        #pragma unroll
        for (int nt = 0; nt < 2; ++nt) {
            f32x4 o = (f32x4){0.f, 0.f, 0.f, 0.f};
            #pragma unroll
            for (int ks = 0; ks < 5; ++ks) {
                const int row  = nt * 16 + m;
                const int slot = ks * 4 + quad;
                const int slog = (slot & ~7) | ((slot & 7) ^ (row & 7));
                const bf16x8 bv = *(const bf16x8*)(buf + row * 384 + slog * 16);
                o = __builtin_amdgcn_mfma_f32_16x16x32_bf16(bv, ac[ks], o, 0, 0, 0);
            }
            *(f32x4*)(Obm + c2 * 32 + nt * 16) = o;    // float4 store
        }
        if (c2 < 15) {
            // guarantee stage(c2+1) drained; allow stage(c2+2)+2 stores to fly
            if (c2 < 14) { WAITVM(5); } else { WAITVM(2); }
            __builtin_amdgcn_s_barrier();
        }
    }
}

// ---------------------------------------------------------------------------
extern "C" void kernel_launch(void* const* d_in, const int* in_sizes, int n_in,
                              void* d_out, int out_size, void* d_ws, size_t ws_size,
                              hipStream_t stream) {
    const float* Q  = (const float*)d_in[0];
    const float* K  = (const float*)d_in[1];
    const float* V  = (const float*)d_in[2];
    const float* SW = (const float*)d_in[4];
    const float* ST = (const float*)d_in[5];
    float* Out = (float*)d_out;
    short* ws  = (short*)d_ws;

    ufa_prep<<<dim3(1152 + 256), dim3(256), 0, stream>>>(K, V, ws);
    ufa_main<<<dim3(512), dim3(256), 0, stream>>>(Q, ws, SW, ST, Out);
}